// Round 1
// baseline (5570.074 us; speedup 1.0000x reference)
//
#include <hip/hip_runtime.h>

typedef __bf16 bf16x8 __attribute__((ext_vector_type(8)));
typedef float f32x4 __attribute__((ext_vector_type(4)));
typedef unsigned short u16;
typedef unsigned int u32;

// ---------------- helpers ----------------
__device__ __forceinline__ u16 f2b(float f) {
    union { float f; u32 u; } v; v.f = f;
    u32 r = v.u + 0x7fffu + ((v.u >> 16) & 1u);
    return (u16)(r >> 16);
}
__device__ __forceinline__ float b2f(u16 u) {
    union { u32 u; float f; } v; v.u = ((u32)u) << 16; return v.f;
}
__device__ __forceinline__ float b2f_lo(u32 u){ union { u32 u; float f; } v; v.u = u << 16; return v.f; }
__device__ __forceinline__ float b2f_hi(u32 u){ union { u32 u; float f; } v; v.u = u & 0xffff0000u; return v.f; }

// ---------------- LN (+shift+window-partition) ----------------
// mode 0: ln1 + optional shift + window partition -> winb bf16 [widx*128+n][256]
// mode 1: ln2 plain -> winb bf16 [token][256]
__global__ __launch_bounds__(256) void ln_kernel(
    const float* __restrict__ h, u16* __restrict__ out,
    const float* __restrict__ g, const float* __restrict__ bb,
    int D, int dsh, int shifted, int mode)
{
    const int lane = threadIdx.x & 63;
    const int t = blockIdx.x * 4 + (threadIdx.x >> 6);
    const float4 xv = *(const float4*)(h + (size_t)t * 256 + lane * 4);
    float s = xv.x + xv.y + xv.z + xv.w;
    float s2 = xv.x*xv.x + xv.y*xv.y + xv.z*xv.z + xv.w*xv.w;
    #pragma unroll
    for (int o = 32; o > 0; o >>= 1) { s += __shfl_xor(s, o); s2 += __shfl_xor(s2, o); }
    const float mu = s * 0.00390625f;
    const float var = s2 * 0.00390625f - mu * mu;
    const float rs = 1.0f / sqrtf(var + 1e-5f);
    const int c0 = lane * 4;
    const float4 gv = *(const float4*)(g + c0);
    const float4 bv = *(const float4*)(bb + c0);
    ushort4 o4;
    o4.x = f2b((xv.x - mu) * rs * gv.x + bv.x);
    o4.y = f2b((xv.y - mu) * rs * gv.y + bv.y);
    o4.z = f2b((xv.z - mu) * rs * gv.z + bv.z);
    o4.w = f2b((xv.w - mu) * rs * gv.w + bv.w);
    size_t oidx;
    if (mode == 1) {
        oidx = (size_t)t * 256 + c0;
    } else {
        const int b = t >> (dsh + 12);
        const int rem = t & ((1 << (dsh + 12)) - 1);
        int d = rem >> 12;
        const int l = rem & 4095;
        int hh = l >> 6, ww = l & 63;
        if (shifted) { d = d ? d - 1 : D - 1; hh = (hh - 4) & 63; ww = (ww - 4) & 63; }
        // nWb = (D/2)*64 = 1<<(dsh+5)
        const int widx = (b << (dsh + 5)) + ((d >> 1) << 6) + ((hh >> 3) << 3) + (ww >> 3);
        const int n = ((d & 1) << 6) + ((hh & 7) << 3) + (ww & 7);
        oidx = ((size_t)(widx * 128 + n)) * 256 + c0;
    }
    *(ushort4*)(out + oidx) = o4;
}

// ---------------- fp32 -> bf16 cast ----------------
__global__ __launch_bounds__(256) void cast_kernel(const float* __restrict__ in, u16* __restrict__ out, int n4)
{
    const int i = blockIdx.x * 256 + threadIdx.x;
    if (i >= n4) return;
    const float4 v = ((const float4*)in)[i];
    ushort4 o; o.x = f2b(v.x); o.y = f2b(v.y); o.z = f2b(v.z); o.w = f2b(v.w);
    ((ushort4*)out)[i] = o;
}

// ---------------- weight transpose+cast: dst[n*K+k] = bf16(src[k*N+n]) ----------------
__global__ __launch_bounds__(256) void wt_kernel(const float* __restrict__ src, u16* __restrict__ dst, int K, int N)
{
    const size_t base = (size_t)blockIdx.y * K * N;
    const int idx = blockIdx.x * 256 + threadIdx.x;
    const int k = idx / N, n = idx - k * N;
    dst[base + (size_t)n * K + k] = f2b(src[base + idx]);
}

// ---------------- MFMA bf16 GEMM, 128x128 tile, templated epilogue ----------------
// A bf16 [M][K] row-major; Bt bf16 [N][K] row-major (i.e. B transposed).
struct GemmP {
    const u16* A; const u16* Bt;
    int K;
    const float* bias;
    u16* outb;
    float* outf;
    const float* hin; float* hout;
    int D, shifted, nwsh, row_off;
};

template <int EPI>
__global__ __launch_bounds__(256, 2) void gemm_kernel(GemmP p)
{
    __shared__ __align__(16) u16 As[128 * 40];
    __shared__ __align__(16) u16 Bs[128 * 40];
    const int tid = threadIdx.x;
    const int m0 = blockIdx.x * 128, n0 = blockIdx.y * 128;
    const int K = p.K;
    f32x4 acc[4][4];
    #pragma unroll
    for (int a = 0; a < 4; a++)
        #pragma unroll
        for (int b = 0; b < 4; b++)
            acc[a][b] = f32x4{0.f, 0.f, 0.f, 0.f};

    const int r0 = tid >> 2;
    const int c8 = (tid & 3) * 8;
    const u16* Ag = p.A + (size_t)m0 * K;
    const u16* Bg = p.Bt + (size_t)n0 * K;
    const int lane = tid & 63;
    const int wv = tid >> 6;
    const int wm = (wv & 1) * 64, wn = (wv >> 1) * 64;
    const int l16 = lane & 15, quad = lane >> 4;

    for (int k0 = 0; k0 < K; k0 += 32) {
        const uint4 a0 = *(const uint4*)(Ag + (size_t)r0 * K + k0 + c8);
        const uint4 a1 = *(const uint4*)(Ag + (size_t)(r0 + 64) * K + k0 + c8);
        const uint4 b0 = *(const uint4*)(Bg + (size_t)r0 * K + k0 + c8);
        const uint4 b1 = *(const uint4*)(Bg + (size_t)(r0 + 64) * K + k0 + c8);
        __syncthreads();
        *(uint4*)(As + r0 * 40 + c8) = a0;
        *(uint4*)(As + (r0 + 64) * 40 + c8) = a1;
        *(uint4*)(Bs + r0 * 40 + c8) = b0;
        *(uint4*)(Bs + (r0 + 64) * 40 + c8) = b1;
        __syncthreads();
        bf16x8 af[4], bfr[4];
        #pragma unroll
        for (int mt = 0; mt < 4; mt++) af[mt] = *(const bf16x8*)(As + (wm + mt * 16 + l16) * 40 + quad * 8);
        #pragma unroll
        for (int nt = 0; nt < 4; nt++) bfr[nt] = *(const bf16x8*)(Bs + (wn + nt * 16 + l16) * 40 + quad * 8);
        #pragma unroll
        for (int mt = 0; mt < 4; mt++)
            #pragma unroll
            for (int nt = 0; nt < 4; nt++)
                acc[mt][nt] = __builtin_amdgcn_mfma_f32_16x16x32_bf16(af[mt], bfr[nt], acc[mt][nt], 0, 0, 0);
    }

    #pragma unroll
    for (int mt = 0; mt < 4; mt++) {
        #pragma unroll
        for (int nt = 0; nt < 4; nt++) {
            #pragma unroll
            for (int i = 0; i < 4; i++) {
                const int row = m0 + wm + mt * 16 + quad * 4 + i;
                const int col = n0 + wn + nt * 16 + l16;
                float v = acc[mt][nt][i];
                if constexpr (EPI == 0) { // qkv: +bias, fold 1/sqrt(dh) into q, bf16 out stride 768
                    v += p.bias[col];
                    if (col < 256) v *= 0.125f;
                    p.outb[(size_t)row * 768 + col] = f2b(v);
                } else if constexpr (EPI == 1) { // proj: +bias, window-reverse/unshift scatter, h += v
                    v += p.bias[col];
                    const int widx = row >> 7, n = row & 127;
                    const int b = widx >> p.nwsh, rem = widx & ((1 << p.nwsh) - 1);
                    int dd = ((rem >> 6) << 1) + (n >> 6);
                    int hh = (((rem >> 3) & 7) << 3) + ((n >> 3) & 7);
                    int ww = ((rem & 7) << 3) + (n & 7);
                    if (p.shifted) { dd = (dd + 1 == p.D) ? 0 : dd + 1; hh = (hh + 4) & 63; ww = (ww + 4) & 63; }
                    const size_t idx = ((size_t)((b * p.D + dd) * 4096 + hh * 64 + ww)) * 256 + col;
                    p.hout[idx] = p.hin[idx] + v;
                } else if constexpr (EPI == 2) { // mlp1: +bias, exact gelu, bf16 out stride 1024
                    v += p.bias[col];
                    v = 0.5f * v * (1.0f + erff(v * 0.7071067811865475f));
                    p.outb[(size_t)row * 1024 + col] = f2b(v);
                } else if constexpr (EPI == 3) { // mlp2: +bias, residual (out may be d_out)
                    v += p.bias[col];
                    const size_t idx = (size_t)(p.row_off + row) * 256 + col;
                    p.hout[idx] = p.hin[idx] + v;
                } else { // expand: plain fp32 out stride 512
                    p.outf[(size_t)row * 512 + col] = v;
                }
            }
        }
    }
}

// ---------------- per-(window,head) attention, online softmax ----------------
__global__ __launch_bounds__(128, 2) void attn_kernel(
    const u16* __restrict__ qkv, u16* __restrict__ att,
    const float* __restrict__ rpbp, int D, int shifted, int w0g, int nwsh)
{
    __shared__ __align__(16) float kb[128 * 64];   // 32KB fp32 K
    __shared__ __align__(16) u16 vb[128 * 64];     // 16KB bf16 V
    __shared__ float rb[675];
    __shared__ int lbl[128];

    const int wloc = blockIdx.x;
    const int head = blockIdx.y;
    const int tid = threadIdx.x;
    const u16* base = qkv + (size_t)wloc * 128 * 768;

    #pragma unroll
    for (int itr = 0; itr < 8; itr++) {
        const int id = itr * 128 + tid;
        const int row = id >> 3, part = id & 7;
        const size_t ro = (size_t)row * 768 + head * 64 + part * 8;
        uint4 k4 = *(const uint4*)(base + ro + 256);
        const u16* ku = (const u16*)&k4;
        float* kd = kb + row * 64 + part * 8;
        #pragma unroll
        for (int q = 0; q < 8; q++) kd[q] = b2f(ku[q]);
        *(uint4*)(vb + row * 64 + part * 8) = *(const uint4*)(base + ro + 512);
    }
    for (int j2 = tid; j2 < 675; j2 += 128) rb[j2] = rpbp[j2 * 4 + head];

    const int widx = w0g + wloc;
    const int rem = widx & ((1 << nwsh) - 1);
    const int d0 = rem >> 6, h0 = (rem >> 3) & 7, w0 = rem & 7;
    {
        const int wd = tid >> 6, wh = (tid >> 3) & 7, ww = tid & 7;
        int lv = 0;
        if (shifted) {
            const int rd = (d0 < (D >> 1) - 1) ? 0 : (1 + wd);
            const int rh = (h0 < 7) ? 0 : (1 + (wh >= 4));
            const int rw = (w0 < 7) ? 0 : (1 + (ww >= 4));
            lv = rd * 9 + rh * 3 + rw;
        }
        lbl[tid] = lv;
    }
    __syncthreads();

    const int r = tid;
    float qf[64];
    {
        const u16* qp = base + (size_t)r * 768 + head * 64;
        #pragma unroll
        for (int itr = 0; itr < 8; itr++) {
            uint4 q4 = *(const uint4*)(qp + itr * 8);
            const u16* qu = (const u16*)&q4;
            #pragma unroll
            for (int q = 0; q < 8; q++) qf[itr * 8 + q] = b2f(qu[q]);
        }
    }
    const int relbase = ((r >> 6) + 1) * 225 + (((r >> 3) & 7) + 7) * 15 + ((r & 7) + 7);
    const int myl = lbl[r];

    float m = -1e30f, l = 0.0f;
    float acc[64];
    #pragma unroll
    for (int d = 0; d < 64; d++) acc[d] = 0.0f;

    for (int j = 0; j < 128; j++) {
        const float4* kj4 = (const float4*)(kb + j * 64);
        float s0 = 0.f, s1 = 0.f, s2 = 0.f, s3 = 0.f;
        #pragma unroll
        for (int itr = 0; itr < 16; itr++) {
            const float4 k4 = kj4[itr];
            s0 = fmaf(qf[itr*4+0], k4.x, s0);
            s1 = fmaf(qf[itr*4+1], k4.y, s1);
            s2 = fmaf(qf[itr*4+2], k4.z, s2);
            s3 = fmaf(qf[itr*4+3], k4.w, s3);
        }
        const int rel = relbase - (j >> 6) * 225 - ((j >> 3) & 7) * 15 - (j & 7);
        float sv = (s0 + s1) + (s2 + s3) + rb[rel];
        if (myl != lbl[j]) sv -= 100.0f;
        const float mn = fmaxf(m, sv);
        const float al = __expf(m - mn);
        const float pp = __expf(sv - mn);
        m = mn;
        l = l * al + pp;
        const uint4* vj4 = (const uint4*)(vb + j * 64);
        #pragma unroll
        for (int itr = 0; itr < 8; itr++) {
            const uint4 vv = vj4[itr];
            float* a = acc + itr * 8;
            a[0] = a[0] * al + pp * b2f_lo(vv.x);
            a[1] = a[1] * al + pp * b2f_hi(vv.x);
            a[2] = a[2] * al + pp * b2f_lo(vv.y);
            a[3] = a[3] * al + pp * b2f_hi(vv.y);
            a[4] = a[4] * al + pp * b2f_lo(vv.z);
            a[5] = a[5] * al + pp * b2f_hi(vv.z);
            a[6] = a[6] * al + pp * b2f_lo(vv.w);
            a[7] = a[7] * al + pp * b2f_hi(vv.w);
        }
    }
    const float inv = 1.0f / l;
    u16* op = att + (size_t)(wloc * 128 + r) * 256 + head * 64;
    #pragma unroll
    for (int itr = 0; itr < 16; itr++) {
        ushort4 o;
        o.x = f2b(acc[itr*4+0] * inv);
        o.y = f2b(acc[itr*4+1] * inv);
        o.z = f2b(acc[itr*4+2] * inv);
        o.w = f2b(acc[itr*4+3] * inv);
        *(ushort4*)(op + itr * 4) = o;
    }
}

// ---------------- patch-expand LN + reorder ----------------
// typ 0: v-expand (in [B,2,2,L]), typ 1: t-expand (in [B,2,4,L])
__global__ __launch_bounds__(256) void expand_ln_kernel(
    const float* __restrict__ sc, float* __restrict__ hout,
    const float* __restrict__ g, const float* __restrict__ bb,
    int it0, int typ)
{
    const int lane = threadIdx.x & 63;
    const int ot = blockIdx.x * 4 + (threadIdx.x >> 6);
    const int itl = ot >> 1, e = ot & 1;
    const float4 xv = *(const float4*)(sc + (size_t)itl * 512 + e * 256 + lane * 4);
    float s = xv.x + xv.y + xv.z + xv.w;
    float s2 = xv.x*xv.x + xv.y*xv.y + xv.z*xv.z + xv.w*xv.w;
    #pragma unroll
    for (int o = 32; o > 0; o >>= 1) { s += __shfl_xor(s, o); s2 += __shfl_xor(s2, o); }
    const float mu = s * 0.00390625f;
    const float var = s2 * 0.00390625f - mu * mu;
    const float rs = 1.0f / sqrtf(var + 1e-5f);
    const int c0 = lane * 4;
    const float4 gv = *(const float4*)(g + c0);
    const float4 bv = *(const float4*)(bb + c0);
    float4 y;
    y.x = (xv.x - mu) * rs * gv.x + bv.x;
    y.y = (xv.y - mu) * rs * gv.y + bv.y;
    y.z = (xv.z - mu) * rs * gv.z + bv.z;
    y.w = (xv.w - mu) * rs * gv.w + bv.w;
    const int it = it0 + itl;
    size_t otg;
    if (typ == 0) {
        const int b = it >> 14, rr = it & 16383;
        const int t = rr >> 13, v = (rr >> 12) & 1, l = rr & 4095;
        otg = (size_t)(((b * 2 + t) * 4 + v * 2 + e) * 4096 + l);
    } else {
        const int b = it >> 15, rr = it & 32767;
        const int t = rr >> 14, v2 = (rr >> 12) & 3, l = rr & 4095;
        otg = (size_t)(((b * 4 + t * 2 + e) * 4 + v2) * 4096 + l);
    }
    *(float4*)(hout + otg * 256 + c0) = y;
}

// ---------------- host ----------------
extern "C" void kernel_launch(void* const* d_in, const int* in_sizes, int n_in,
                              void* d_out, int out_size, void* d_ws, size_t ws_size,
                              hipStream_t stream)
{
    const float* x      = (const float*)d_in[0];
    const float* n1w    = (const float*)d_in[1];
    const float* n1b    = (const float*)d_in[2];
    const float* qkv_w  = (const float*)d_in[3];
    const float* qkv_b  = (const float*)d_in[4];
    const float* rpb    = (const float*)d_in[5];
    const float* proj_w = (const float*)d_in[6];
    const float* proj_b = (const float*)d_in[7];
    const float* n2w    = (const float*)d_in[8];
    const float* n2b    = (const float*)d_in[9];
    const float* mlp1_w = (const float*)d_in[10];
    const float* mlp1_b = (const float*)d_in[11];
    const float* mlp2_w = (const float*)d_in[12];
    const float* mlp2_b = (const float*)d_in[13];
    const float* expv_w = (const float*)d_in[14];
    const float* expv_nw= (const float*)d_in[15];
    const float* expv_nb= (const float*)d_in[16];
    const float* expt_w = (const float*)d_in[17];
    const float* expt_nw= (const float*)d_in[18];
    const float* expt_nb= (const float*)d_in[19];
    (void)in_sizes; (void)n_in; (void)out_size;

    if (ws_size < 352321536ULL) return; // 336 MB layout below

    char* ws = (char*)d_ws;
    float* h    = (float*)ws;                                   // 134217728 B
    u16*  winb  = (u16*)(ws + 134217728LL);                     // 67108864 B
    u16*  att   = (u16*)(ws + 134217728LL + 67108864LL);        // 67108864 B
    char* scr   = ws + 134217728LL + 2LL * 67108864LL;          // 67108864 B
    u16*  scrb  = (u16*)scr;
    float* scrf = (float*)scr;
    u16* qkvT   = (u16*)(ws + 134217728LL + 3LL * 67108864LL);  // bf16 weights
    u16* projT  = qkvT + 6 * 768 * 256;
    u16* mlp1T  = projT + 6 * 256 * 256;
    u16* mlp2T  = mlp1T + 6 * 1024 * 256;
    u16* expvT  = mlp2T + 6 * 256 * 1024;
    u16* exptT  = expvT + 512 * 256;

    wt_kernel<<<dim3(768, 6), 256, 0, stream>>>(qkv_w, qkvT, 256, 768);
    wt_kernel<<<dim3(256, 6), 256, 0, stream>>>(proj_w, projT, 256, 256);
    wt_kernel<<<dim3(1024, 6), 256, 0, stream>>>(mlp1_w, mlp1T, 256, 1024);
    wt_kernel<<<dim3(1024, 6), 256, 0, stream>>>(mlp2_w, mlp2T, 1024, 256);
    wt_kernel<<<dim3(512, 1), 256, 0, stream>>>(expv_w, expvT, 256, 512);
    wt_kernel<<<dim3(512, 1), 256, 0, stream>>>(expt_w, exptT, 256, 512);
    hipMemcpyAsync(h, x, 33554432ULL, hipMemcpyDeviceToDevice, stream);

    for (int s = 0; s < 3; s++) {
        const int D = 4 << s;
        const int dsh = 2 + s;
        const int nwsh = dsh + 5;     // log2 windows per batch
        const int tokens = 2 * D * 4096;
        const int nch = tokens / 32768;
        for (int j = 0; j < 2; j++) {
            const int i = 2 * s + j;
            ln_kernel<<<dim3(tokens / 4), 256, 0, stream>>>(h, winb, n1w + i * 256, n1b + i * 256, D, dsh, j, 0);
            for (int c = 0; c < nch; c++) {
                GemmP gq{};
                gq.A = winb + (size_t)c * 32768 * 256;
                gq.Bt = qkvT + (size_t)i * 768 * 256;
                gq.K = 256; gq.bias = qkv_b + i * 768; gq.outb = scrb;
                gemm_kernel<0><<<dim3(256, 6), 256, 0, stream>>>(gq);
                attn_kernel<<<dim3(256, 4), 128, 0, stream>>>(scrb, att + (size_t)c * 32768 * 256,
                                                              rpb + i * 675 * 4, D, j, c * 256, nwsh);
            }
            GemmP gp{};
            gp.A = att; gp.Bt = projT + (size_t)i * 256 * 256; gp.K = 256;
            gp.bias = proj_b + i * 256; gp.hin = h; gp.hout = h;
            gp.D = D; gp.shifted = j; gp.nwsh = nwsh;
            gemm_kernel<1><<<dim3(tokens / 128, 2), 256, 0, stream>>>(gp);
            ln_kernel<<<dim3(tokens / 4), 256, 0, stream>>>(h, winb, n2w + i * 256, n2b + i * 256, D, dsh, 0, 1);
            for (int c = 0; c < nch; c++) {
                GemmP g1{};
                g1.A = winb + (size_t)c * 32768 * 256;
                g1.Bt = mlp1T + (size_t)i * 1024 * 256;
                g1.K = 256; g1.bias = mlp1_b + i * 1024; g1.outb = scrb;
                gemm_kernel<2><<<dim3(256, 8), 256, 0, stream>>>(g1);
                GemmP g2{};
                g2.A = scrb; g2.Bt = mlp2T + (size_t)i * 256 * 1024; g2.K = 1024;
                g2.bias = mlp2_b + i * 256; g2.hin = h; g2.row_off = c * 32768;
                g2.hout = (s == 2 && j == 1) ? (float*)d_out : h;
                gemm_kernel<3><<<dim3(256, 2), 256, 0, stream>>>(g2);
            }
        }
        if (s < 2) {
            const int ntok = tokens;
            cast_kernel<<<dim3(ntok * 64 / 256), 256, 0, stream>>>(h, winb, ntok * 64);
            const u16* eT = (s == 0) ? expvT : exptT;
            const float* eg = (s == 0) ? expv_nw : expt_nw;
            const float* eb = (s == 0) ? expv_nb : expt_nb;
            for (int c = 0; c < ntok / 32768; c++) {
                GemmP ge{};
                ge.A = winb + (size_t)c * 32768 * 256; ge.Bt = eT; ge.K = 256; ge.outf = scrf;
                gemm_kernel<4><<<dim3(256, 4), 256, 0, stream>>>(ge);
                expand_ln_kernel<<<dim3(16384), 256, 0, stream>>>(scrf, h, eg, eb, c * 32768, s);
            }
        }
    }
}

// Round 2
// 3006.094 us; speedup vs baseline: 1.8529x; 1.8529x over previous
//
#include <hip/hip_runtime.h>

typedef __bf16 bf16x8 __attribute__((ext_vector_type(8)));
typedef float f32x4 __attribute__((ext_vector_type(4)));
typedef unsigned short u16;
typedef unsigned int u32;

// ---------------- helpers ----------------
__device__ __forceinline__ u16 f2b(float f) {
    union { float f; u32 u; } v; v.f = f;
    u32 r = v.u + 0x7fffu + ((v.u >> 16) & 1u);
    return (u16)(r >> 16);
}
__device__ __forceinline__ float b2f(u16 u) {
    union { u32 u; float f; } v; v.u = ((u32)u) << 16; return v.f;
}

// ---------------- LN (+shift+window-partition) ----------------
__global__ __launch_bounds__(256) void ln_kernel(
    const float* __restrict__ h, u16* __restrict__ out,
    const float* __restrict__ g, const float* __restrict__ bb,
    int D, int dsh, int shifted, int mode)
{
    const int lane = threadIdx.x & 63;
    const int t = blockIdx.x * 4 + (threadIdx.x >> 6);
    const float4 xv = *(const float4*)(h + (size_t)t * 256 + lane * 4);
    float s = xv.x + xv.y + xv.z + xv.w;
    float s2 = xv.x*xv.x + xv.y*xv.y + xv.z*xv.z + xv.w*xv.w;
    #pragma unroll
    for (int o = 32; o > 0; o >>= 1) { s += __shfl_xor(s, o); s2 += __shfl_xor(s2, o); }
    const float mu = s * 0.00390625f;
    const float var = s2 * 0.00390625f - mu * mu;
    const float rs = 1.0f / sqrtf(var + 1e-5f);
    const int c0 = lane * 4;
    const float4 gv = *(const float4*)(g + c0);
    const float4 bv = *(const float4*)(bb + c0);
    ushort4 o4;
    o4.x = f2b((xv.x - mu) * rs * gv.x + bv.x);
    o4.y = f2b((xv.y - mu) * rs * gv.y + bv.y);
    o4.z = f2b((xv.z - mu) * rs * gv.z + bv.z);
    o4.w = f2b((xv.w - mu) * rs * gv.w + bv.w);
    size_t oidx;
    if (mode == 1) {
        oidx = (size_t)t * 256 + c0;
    } else {
        const int b = t >> (dsh + 12);
        const int rem = t & ((1 << (dsh + 12)) - 1);
        int d = rem >> 12;
        const int l = rem & 4095;
        int hh = l >> 6, ww = l & 63;
        if (shifted) { d = d ? d - 1 : D - 1; hh = (hh - 4) & 63; ww = (ww - 4) & 63; }
        const int widx = (b << (dsh + 5)) + ((d >> 1) << 6) + ((hh >> 3) << 3) + (ww >> 3);
        const int n = ((d & 1) << 6) + ((hh & 7) << 3) + (ww & 7);
        oidx = ((size_t)(widx * 128 + n)) * 256 + c0;
    }
    *(ushort4*)(out + oidx) = o4;
}

// ---------------- fp32 -> bf16 cast ----------------
__global__ __launch_bounds__(256) void cast_kernel(const float* __restrict__ in, u16* __restrict__ out, int n4)
{
    const int i = blockIdx.x * 256 + threadIdx.x;
    if (i >= n4) return;
    const float4 v = ((const float4*)in)[i];
    ushort4 o; o.x = f2b(v.x); o.y = f2b(v.y); o.z = f2b(v.z); o.w = f2b(v.w);
    ((ushort4*)out)[i] = o;
}

// ---------------- weight transpose+cast ----------------
__global__ __launch_bounds__(256) void wt_kernel(const float* __restrict__ src, u16* __restrict__ dst, int K, int N)
{
    const size_t base = (size_t)blockIdx.y * K * N;
    const int idx = blockIdx.x * 256 + threadIdx.x;
    const int k = idx / N, n = idx - k * N;
    dst[base + (size_t)n * K + k] = f2b(src[base + idx]);
}

// ---------------- MFMA bf16 GEMM, 128x128 tile, templated epilogue ----------------
struct GemmP {
    const u16* A; const u16* Bt;
    int K;
    const float* bias;
    u16* outb;
    float* outf;
    const float* hin; float* hout;
    int D, shifted, nwsh, row_off;
};

template <int EPI>
__global__ __launch_bounds__(256, 2) void gemm_kernel(GemmP p)
{
    __shared__ __align__(16) u16 As[128 * 40];
    __shared__ __align__(16) u16 Bs[128 * 40];
    const int tid = threadIdx.x;
    const int m0 = blockIdx.x * 128, n0 = blockIdx.y * 128;
    const int K = p.K;
    f32x4 acc[4][4];
    #pragma unroll
    for (int a = 0; a < 4; a++)
        #pragma unroll
        for (int b = 0; b < 4; b++)
            acc[a][b] = f32x4{0.f, 0.f, 0.f, 0.f};

    const int r0 = tid >> 2;
    const int c8 = (tid & 3) * 8;
    const u16* Ag = p.A + (size_t)m0 * K;
    const u16* Bg = p.Bt + (size_t)n0 * K;
    const int lane = tid & 63;
    const int wv = tid >> 6;
    const int wm = (wv & 1) * 64, wn = (wv >> 1) * 64;
    const int l16 = lane & 15, quad = lane >> 4;

    for (int k0 = 0; k0 < K; k0 += 32) {
        const uint4 a0 = *(const uint4*)(Ag + (size_t)r0 * K + k0 + c8);
        const uint4 a1 = *(const uint4*)(Ag + (size_t)(r0 + 64) * K + k0 + c8);
        const uint4 b0 = *(const uint4*)(Bg + (size_t)r0 * K + k0 + c8);
        const uint4 b1 = *(const uint4*)(Bg + (size_t)(r0 + 64) * K + k0 + c8);
        __syncthreads();
        *(uint4*)(As + r0 * 40 + c8) = a0;
        *(uint4*)(As + (r0 + 64) * 40 + c8) = a1;
        *(uint4*)(Bs + r0 * 40 + c8) = b0;
        *(uint4*)(Bs + (r0 + 64) * 40 + c8) = b1;
        __syncthreads();
        bf16x8 af[4], bfr[4];
        #pragma unroll
        for (int mt = 0; mt < 4; mt++) af[mt] = *(const bf16x8*)(As + (wm + mt * 16 + l16) * 40 + quad * 8);
        #pragma unroll
        for (int nt = 0; nt < 4; nt++) bfr[nt] = *(const bf16x8*)(Bs + (wn + nt * 16 + l16) * 40 + quad * 8);
        #pragma unroll
        for (int mt = 0; mt < 4; mt++)
            #pragma unroll
            for (int nt = 0; nt < 4; nt++)
                acc[mt][nt] = __builtin_amdgcn_mfma_f32_16x16x32_bf16(af[mt], bfr[nt], acc[mt][nt], 0, 0, 0);
    }

    #pragma unroll
    for (int mt = 0; mt < 4; mt++) {
        #pragma unroll
        for (int nt = 0; nt < 4; nt++) {
            #pragma unroll
            for (int i = 0; i < 4; i++) {
                const int row = m0 + wm + mt * 16 + quad * 4 + i;
                const int col = n0 + wn + nt * 16 + l16;
                float v = acc[mt][nt][i];
                if constexpr (EPI == 0) { // qkv
                    v += p.bias[col];
                    if (col < 256) v *= 0.125f;
                    p.outb[(size_t)row * 768 + col] = f2b(v);
                } else if constexpr (EPI == 1) { // proj + window-reverse + residual
                    v += p.bias[col];
                    const int widx = row >> 7, n = row & 127;
                    const int b = widx >> p.nwsh, rem = widx & ((1 << p.nwsh) - 1);
                    int dd = ((rem >> 6) << 1) + (n >> 6);
                    int hh = (((rem >> 3) & 7) << 3) + ((n >> 3) & 7);
                    int ww = ((rem & 7) << 3) + (n & 7);
                    if (p.shifted) { dd = (dd + 1 == p.D) ? 0 : dd + 1; hh = (hh + 4) & 63; ww = (ww + 4) & 63; }
                    const size_t idx = ((size_t)((b * p.D + dd) * 4096 + hh * 64 + ww)) * 256 + col;
                    p.hout[idx] = p.hin[idx] + v;
                } else if constexpr (EPI == 2) { // mlp1 + gelu
                    v += p.bias[col];
                    v = 0.5f * v * (1.0f + erff(v * 0.7071067811865475f));
                    p.outb[(size_t)row * 1024 + col] = f2b(v);
                } else if constexpr (EPI == 3) { // mlp2 + residual
                    v += p.bias[col];
                    const size_t idx = (size_t)(p.row_off + row) * 256 + col;
                    p.hout[idx] = p.hin[idx] + v;
                } else { // expand
                    p.outf[(size_t)row * 512 + col] = v;
                }
            }
        }
    }
}

// ---------------- MFMA attention: one block per (window, head) ----------------
// 4 waves; wave wq owns Q rows [wq*32, wq*32+32). Full-row softmax (no online).
// LDS: Qs[128][72]b16 | Ks[128][72]b16, overlaid later by Ps[128][136]b16; Vt[64][136]b16; rb[675]; lbl[128]
__global__ __launch_bounds__(256, 2) void attn_mfma_kernel(
    const u16* __restrict__ qkv, u16* __restrict__ att,
    const float* __restrict__ rpbp, int D, int shifted, int w0g, int nwsh)
{
    __shared__ __align__(16) char smem[57856];
    u16* Qs = (u16*)smem;                       // 128*72 u16 = 18432 B
    u16* Ks = (u16*)(smem + 18432);             // 18432 B
    u16* Ps = (u16*)smem;                       // 128*136 u16 = 34816 B (overlays Qs+Ks)
    u16* Vt = (u16*)(smem + 36864);             // 64*136 u16 = 17408 B
    float* rb = (float*)(smem + 54272);         // 2700 B
    int* lbl = (int*)(smem + 56972);            // 512 B

    const int wloc = blockIdx.x;
    const int head = blockIdx.y;
    const int tid = threadIdx.x;
    const u16* base = qkv + (size_t)wloc * 98304; // 128*768

    #pragma unroll
    for (int it = 0; it < 4; it++) {
        const int id = it * 256 + tid;          // 0..1023
        const int row = id >> 3, oct = id & 7;
        const size_t ro = (size_t)row * 768 + head * 64 + oct * 8;
        *(uint4*)(Qs + row * 72 + oct * 8) = *(const uint4*)(base + ro);
        *(uint4*)(Ks + row * 72 + oct * 8) = *(const uint4*)(base + ro + 256);
        uint4 vv = *(const uint4*)(base + ro + 512);
        const u16* vp = (const u16*)&vv;
        #pragma unroll
        for (int q = 0; q < 8; q++) Vt[(oct * 8 + q) * 136 + row] = vp[q];
    }
    for (int j = tid; j < 675; j += 256) rb[j] = rpbp[j * 4 + head];
    if (tid < 128) {
        int lv = 0;
        if (shifted) {
            const int widx = w0g + wloc;
            const int rem = widx & ((1 << nwsh) - 1);
            const int d0 = rem >> 6, h0 = (rem >> 3) & 7, w0 = rem & 7;
            const int wd = tid >> 6, wh = (tid >> 3) & 7, ww = tid & 7;
            const int rd = (d0 < (D >> 1) - 1) ? 0 : (1 + wd);
            const int rh = (h0 < 7) ? 0 : (1 + (wh >= 4));
            const int rw = (w0 < 7) ? 0 : (1 + (ww >= 4));
            lv = rd * 9 + rh * 3 + rw;
        }
        lbl[tid] = lv;
    }
    __syncthreads();

    const int wq = tid >> 6;
    const int lane = tid & 63;
    const int l16 = lane & 15, quad = lane >> 4;
    const int myrow0 = wq * 32;

    // S = Q K^T  (scale already folded into q by qkv epilogue)
    f32x4 sc[2][8];
    #pragma unroll
    for (int mt = 0; mt < 2; mt++)
        #pragma unroll
        for (int nt = 0; nt < 8; nt++)
            sc[mt][nt] = f32x4{0.f, 0.f, 0.f, 0.f};
    #pragma unroll
    for (int kt = 0; kt < 2; kt++) {
        bf16x8 aq[2];
        #pragma unroll
        for (int mt = 0; mt < 2; mt++)
            aq[mt] = *(const bf16x8*)(Qs + (myrow0 + mt * 16 + l16) * 72 + kt * 32 + quad * 8);
        bf16x8 bk[8];
        #pragma unroll
        for (int nt = 0; nt < 8; nt++)
            bk[nt] = *(const bf16x8*)(Ks + (nt * 16 + l16) * 72 + kt * 32 + quad * 8);
        #pragma unroll
        for (int mt = 0; mt < 2; mt++)
            #pragma unroll
            for (int nt = 0; nt < 8; nt++)
                sc[mt][nt] = __builtin_amdgcn_mfma_f32_16x16x32_bf16(aq[mt], bk[nt], sc[mt][nt], 0, 0, 0);
    }

    // softmax over full rows (rpb + shift mask folded in); P kept in sc
    float linv[2][4];
    #pragma unroll
    for (int mt = 0; mt < 2; mt++) {
        #pragma unroll
        for (int i = 0; i < 4; i++) {
            const int row = myrow0 + mt * 16 + quad * 4 + i;
            const int rbase = ((row >> 6) + 1) * 225 + (((row >> 3) & 7) + 7) * 15 + ((row & 7) + 7);
            const int lq = lbl[row];
            float mx = -1e30f;
            float sv[8];
            #pragma unroll
            for (int nt = 0; nt < 8; nt++) {
                const int col = nt * 16 + l16;
                float v = sc[mt][nt][i] + rb[rbase - (col >> 6) * 225 - ((col >> 3) & 7) * 15 - (col & 7)];
                if (shifted && lq != lbl[col]) v -= 100.0f;
                sv[nt] = v;
                mx = fmaxf(mx, v);
            }
            #pragma unroll
            for (int o = 1; o < 16; o <<= 1) mx = fmaxf(mx, __shfl_xor(mx, o));
            float l = 0.0f;
            #pragma unroll
            for (int nt = 0; nt < 8; nt++) {
                const float pp = __expf(sv[nt] - mx);
                sc[mt][nt][i] = pp;
                l += pp;
            }
            #pragma unroll
            for (int o = 1; o < 16; o <<= 1) l += __shfl_xor(l, o);
            linv[mt][i] = 1.0f / l;
        }
    }

    __syncthreads();  // all waves done reading Qs/Ks before Ps overlays them
    #pragma unroll
    for (int mt = 0; mt < 2; mt++)
        #pragma unroll
        for (int nt = 0; nt < 8; nt++)
            #pragma unroll
            for (int i = 0; i < 4; i++)
                Ps[(myrow0 + mt * 16 + quad * 4 + i) * 136 + nt * 16 + l16] = f2b(sc[mt][nt][i]);
    // each wave reads only its own Ps rows -> no barrier needed (lgkmcnt orders within wave)

    // O = P V
    f32x4 oc[2][4];
    #pragma unroll
    for (int mt = 0; mt < 2; mt++)
        #pragma unroll
        for (int nt = 0; nt < 4; nt++)
            oc[mt][nt] = f32x4{0.f, 0.f, 0.f, 0.f};
    #pragma unroll
    for (int kt = 0; kt < 4; kt++) {
        bf16x8 ap[2];
        #pragma unroll
        for (int mt = 0; mt < 2; mt++)
            ap[mt] = *(const bf16x8*)(Ps + (myrow0 + mt * 16 + l16) * 136 + kt * 32 + quad * 8);
        bf16x8 bv[4];
        #pragma unroll
        for (int nt = 0; nt < 4; nt++)
            bv[nt] = *(const bf16x8*)(Vt + (nt * 16 + l16) * 136 + kt * 32 + quad * 8);
        #pragma unroll
        for (int mt = 0; mt < 2; mt++)
            #pragma unroll
            for (int nt = 0; nt < 4; nt++)
                oc[mt][nt] = __builtin_amdgcn_mfma_f32_16x16x32_bf16(ap[mt], bv[nt], oc[mt][nt], 0, 0, 0);
    }

    #pragma unroll
    for (int mt = 0; mt < 2; mt++)
        #pragma unroll
        for (int nt = 0; nt < 4; nt++)
            #pragma unroll
            for (int i = 0; i < 4; i++) {
                const int row = myrow0 + mt * 16 + quad * 4 + i;
                const int col = nt * 16 + l16;
                att[(size_t)(wloc * 128 + row) * 256 + head * 64 + col] = f2b(oc[mt][nt][i] * linv[mt][i]);
            }
}

// ---------------- patch-expand LN + reorder ----------------
__global__ __launch_bounds__(256) void expand_ln_kernel(
    const float* __restrict__ sc, float* __restrict__ hout,
    const float* __restrict__ g, const float* __restrict__ bb,
    int it0, int typ)
{
    const int lane = threadIdx.x & 63;
    const int ot = blockIdx.x * 4 + (threadIdx.x >> 6);
    const int itl = ot >> 1, e = ot & 1;
    const float4 xv = *(const float4*)(sc + (size_t)itl * 512 + e * 256 + lane * 4);
    float s = xv.x + xv.y + xv.z + xv.w;
    float s2 = xv.x*xv.x + xv.y*xv.y + xv.z*xv.z + xv.w*xv.w;
    #pragma unroll
    for (int o = 32; o > 0; o >>= 1) { s += __shfl_xor(s, o); s2 += __shfl_xor(s2, o); }
    const float mu = s * 0.00390625f;
    const float var = s2 * 0.00390625f - mu * mu;
    const float rs = 1.0f / sqrtf(var + 1e-5f);
    const int c0 = lane * 4;
    const float4 gv = *(const float4*)(g + c0);
    const float4 bv = *(const float4*)(bb + c0);
    float4 y;
    y.x = (xv.x - mu) * rs * gv.x + bv.x;
    y.y = (xv.y - mu) * rs * gv.y + bv.y;
    y.z = (xv.z - mu) * rs * gv.z + bv.z;
    y.w = (xv.w - mu) * rs * gv.w + bv.w;
    const int it = it0 + itl;
    size_t otg;
    if (typ == 0) {
        const int b = it >> 14, rr = it & 16383;
        const int t = rr >> 13, v = (rr >> 12) & 1, l = rr & 4095;
        otg = (size_t)(((b * 2 + t) * 4 + v * 2 + e) * 4096 + l);
    } else {
        const int b = it >> 15, rr = it & 32767;
        const int t = rr >> 14, v2 = (rr >> 12) & 3, l = rr & 4095;
        otg = (size_t)(((b * 4 + t * 2 + e) * 4 + v2) * 4096 + l);
    }
    *(float4*)(hout + otg * 256 + c0) = y;
}

// ---------------- host ----------------
extern "C" void kernel_launch(void* const* d_in, const int* in_sizes, int n_in,
                              void* d_out, int out_size, void* d_ws, size_t ws_size,
                              hipStream_t stream)
{
    const float* x      = (const float*)d_in[0];
    const float* n1w    = (const float*)d_in[1];
    const float* n1b    = (const float*)d_in[2];
    const float* qkv_w  = (const float*)d_in[3];
    const float* qkv_b  = (const float*)d_in[4];
    const float* rpb    = (const float*)d_in[5];
    const float* proj_w = (const float*)d_in[6];
    const float* proj_b = (const float*)d_in[7];
    const float* n2w    = (const float*)d_in[8];
    const float* n2b    = (const float*)d_in[9];
    const float* mlp1_w = (const float*)d_in[10];
    const float* mlp1_b = (const float*)d_in[11];
    const float* mlp2_w = (const float*)d_in[12];
    const float* mlp2_b = (const float*)d_in[13];
    const float* expv_w = (const float*)d_in[14];
    const float* expv_nw= (const float*)d_in[15];
    const float* expv_nb= (const float*)d_in[16];
    const float* expt_w = (const float*)d_in[17];
    const float* expt_nw= (const float*)d_in[18];
    const float* expt_nb= (const float*)d_in[19];
    (void)in_sizes; (void)n_in; (void)out_size;

    if (ws_size < 352321536ULL) return;

    char* ws = (char*)d_ws;
    float* h    = (float*)ws;                                   // 134217728 B
    u16*  winb  = (u16*)(ws + 134217728LL);                     // 67108864 B
    u16*  att   = (u16*)(ws + 134217728LL + 67108864LL);        // 67108864 B
    char* scr   = ws + 134217728LL + 2LL * 67108864LL;          // 67108864 B
    u16*  scrb  = (u16*)scr;
    float* scrf = (float*)scr;
    u16* qkvT   = (u16*)(ws + 134217728LL + 3LL * 67108864LL);
    u16* projT  = qkvT + 6 * 768 * 256;
    u16* mlp1T  = projT + 6 * 256 * 256;
    u16* mlp2T  = mlp1T + 6 * 1024 * 256;
    u16* expvT  = mlp2T + 6 * 256 * 1024;
    u16* exptT  = expvT + 512 * 256;

    wt_kernel<<<dim3(768, 6), 256, 0, stream>>>(qkv_w, qkvT, 256, 768);
    wt_kernel<<<dim3(256, 6), 256, 0, stream>>>(proj_w, projT, 256, 256);
    wt_kernel<<<dim3(1024, 6), 256, 0, stream>>>(mlp1_w, mlp1T, 256, 1024);
    wt_kernel<<<dim3(1024, 6), 256, 0, stream>>>(mlp2_w, mlp2T, 1024, 256);
    wt_kernel<<<dim3(512, 1), 256, 0, stream>>>(expv_w, expvT, 256, 512);
    wt_kernel<<<dim3(512, 1), 256, 0, stream>>>(expt_w, exptT, 256, 512);
    hipMemcpyAsync(h, x, 33554432ULL, hipMemcpyDeviceToDevice, stream);

    for (int s = 0; s < 3; s++) {
        const int D = 4 << s;
        const int dsh = 2 + s;
        const int nwsh = dsh + 5;
        const int tokens = 2 * D * 4096;
        const int nch = tokens / 32768;
        for (int j = 0; j < 2; j++) {
            const int i = 2 * s + j;
            ln_kernel<<<dim3(tokens / 4), 256, 0, stream>>>(h, winb, n1w + i * 256, n1b + i * 256, D, dsh, j, 0);
            for (int c = 0; c < nch; c++) {
                GemmP gq{};
                gq.A = winb + (size_t)c * 32768 * 256;
                gq.Bt = qkvT + (size_t)i * 768 * 256;
                gq.K = 256; gq.bias = qkv_b + i * 768; gq.outb = scrb;
                gemm_kernel<0><<<dim3(256, 6), 256, 0, stream>>>(gq);
                attn_mfma_kernel<<<dim3(256, 4), 256, 0, stream>>>(scrb, att + (size_t)c * 32768 * 256,
                                                                   rpb + i * 675 * 4, D, j, c * 256, nwsh);
            }
            GemmP gp{};
            gp.A = att; gp.Bt = projT + (size_t)i * 256 * 256; gp.K = 256;
            gp.bias = proj_b + i * 256; gp.hin = h; gp.hout = h;
            gp.D = D; gp.shifted = j; gp.nwsh = nwsh;
            gemm_kernel<1><<<dim3(tokens / 128, 2), 256, 0, stream>>>(gp);
            ln_kernel<<<dim3(tokens / 4), 256, 0, stream>>>(h, winb, n2w + i * 256, n2b + i * 256, D, dsh, 0, 1);
            for (int c = 0; c < nch; c++) {
                GemmP g1{};
                g1.A = winb + (size_t)c * 32768 * 256;
                g1.Bt = mlp1T + (size_t)i * 1024 * 256;
                g1.K = 256; g1.bias = mlp1_b + i * 1024; g1.outb = scrb;
                gemm_kernel<2><<<dim3(256, 8), 256, 0, stream>>>(g1);
                GemmP g2{};
                g2.A = scrb; g2.Bt = mlp2T + (size_t)i * 256 * 1024; g2.K = 1024;
                g2.bias = mlp2_b + i * 256; g2.hin = h; g2.row_off = c * 32768;
                g2.hout = (s == 2 && j == 1) ? (float*)d_out : h;
                gemm_kernel<3><<<dim3(256, 2), 256, 0, stream>>>(g2);
            }
        }
        if (s < 2) {
            const int ntok = tokens;
            cast_kernel<<<dim3(ntok * 64 / 256), 256, 0, stream>>>(h, winb, ntok * 64);
            const u16* eT = (s == 0) ? expvT : exptT;
            const float* eg = (s == 0) ? expv_nw : expt_nw;
            const float* eb = (s == 0) ? expv_nb : expt_nb;
            for (int c = 0; c < ntok / 32768; c++) {
                GemmP ge{};
                ge.A = winb + (size_t)c * 32768 * 256; ge.Bt = eT; ge.K = 256; ge.outf = scrf;
                gemm_kernel<4><<<dim3(256, 4), 256, 0, stream>>>(ge);
                expand_ln_kernel<<<dim3(16384), 256, 0, stream>>>(scrf, h, eg, eb, c * 32768, s);
            }
        }
    }
}